// Round 2
// baseline (102.746 us; speedup 1.0000x reference)
//
#include <hip/hip_runtime.h>
#include <math.h>

#define N_ROWS 2048
#define D_DIM 512
#define P_DIM 10

__device__ inline float wave_reduce_f(float v) {
#pragma unroll
  for (int off = 32; off > 0; off >>= 1) v += __shfl_down(v, off, 64);
  return v;
}

__device__ inline double wave_reduce_d(double v) {
#pragma unroll
  for (int off = 32; off > 0; off >>= 1) v += __shfl_down(v, off, 64);
  return v;
}

// Compiler-only scheduling fence for wave-lockstep LDS stages (no s_barrier).
// DS ops from a single wave are processed in order by HW; this just stops the
// compiler from reordering/caching LDS accesses across the stage boundary.
__device__ inline void wave_lds_fence() {
  asm volatile("" ::: "memory");
  __builtin_amdgcn_wave_barrier();
  asm volatile("" ::: "memory");
}

// K1: wave-per-row. post_cm[p][row] = z[row,:]@proj[:,p],
// prior_cm[p][row] = (g[row,:]/max(||g row||,eps))@proj[:,p].
// float4 global loads; proj staged in LDS swizzled as
// slot(p,e) = p*512 + (e&3)*128 + (e>>2) so that for fixed (c,m) the 64 lanes
// read 64 consecutive slots (2 lanes/bank = free). Block 0 also zeroes d_out
// (required: harness re-poisons d_out to 0xAA before every timed launch and
// K2 accumulates into it with atomics).
__global__ __launch_bounds__(256) void rc_proj_kernel(
    const float4* __restrict__ z4, const float4* __restrict__ g4,
    const float* __restrict__ proj, float* __restrict__ post_cm,
    float* __restrict__ prior_cm, float* __restrict__ out) {
  __shared__ float pl[P_DIM * D_DIM];  // 20 KiB
  for (int i = threadIdx.x; i < P_DIM * D_DIM; i += 256) {
    int e = i / P_DIM, p = i - e * P_DIM;  // proj is [D][P] row-major
    pl[p * D_DIM + (e & 3) * 128 + (e >> 2)] = proj[i];
  }
  if (blockIdx.x == 0 && threadIdx.x == 0) out[0] = 0.f;
  __syncthreads();
  const int wave = threadIdx.x >> 6, lane = threadIdx.x & 63;
  const int row = blockIdx.x * 4 + wave;
  const float4* zr = z4 + (size_t)row * (D_DIM / 4);
  const float4* gr = g4 + (size_t)row * (D_DIM / 4);
  // lane holds float4 #(lane + 64m), m=0,1 -> elements e = 4*(lane+64m)+c
  float4 zv[2], gv[2];
  zv[0] = zr[lane];
  zv[1] = zr[64 + lane];
  gv[0] = gr[lane];
  gv[1] = gr[64 + lane];
  float n2 = gv[0].x * gv[0].x + gv[0].y * gv[0].y + gv[0].z * gv[0].z +
             gv[0].w * gv[0].w + gv[1].x * gv[1].x + gv[1].y * gv[1].y +
             gv[1].z * gv[1].z + gv[1].w * gv[1].w;
  float az[P_DIM], ag[P_DIM];
#pragma unroll
  for (int p = 0; p < P_DIM; ++p) { az[p] = 0.f; ag[p] = 0.f; }
#pragma unroll
  for (int m = 0; m < 2; ++m) {
    const float zc[4] = {zv[m].x, zv[m].y, zv[m].z, zv[m].w};
    const float gc[4] = {gv[m].x, gv[m].y, gv[m].z, gv[m].w};
#pragma unroll
    for (int c = 0; c < 4; ++c) {
#pragma unroll
      for (int p = 0; p < P_DIM; ++p) {
        float w = pl[p * D_DIM + c * 128 + m * 64 + lane];
        az[p] += zc[c] * w;
        ag[p] += gc[c] * w;
      }
    }
  }
#pragma unroll
  for (int p = 0; p < P_DIM; ++p) {
    az[p] = wave_reduce_f(az[p]);
    ag[p] = wave_reduce_f(ag[p]);
  }
  n2 = wave_reduce_f(n2);
  if (lane == 0) {
    float inv = 1.f / fmaxf(sqrtf(n2), 1e-12f);
#pragma unroll
    for (int p = 0; p < P_DIM; ++p) {
      post_cm[p * N_ROWS + row] = az[p];
      prior_cm[p * N_ROWS + row] = ag[p] * inv;
    }
  }
}

// Closed-form fgw from shared + variant sums.
// s_i=a_i^2-b_i^2; gw*n^2 = 2n*Ss2 + 2*Ss^2 - 8*(Ssa*Sa - Ssb*Sb)
//                           + 4*(Sa2^2 - 2*Sab^2 + Sb2^2)
// with Ss2 = Sa4-2*U4+Sb4, Ss = Sa2-Sb2, Ssa = Sa3-U3, Ssb = U2-Sb3,
// Sab = U1; w = Sa2+Sb2-2*U1.
__device__ inline double fgw_eval(double Sa, double Sb, double Sa2, double Sb2,
                                  double Sa3, double Sb3, double Sa4,
                                  double Sb4, double U1, double U2, double U3,
                                  double U4) {
  const double n = (double)N_ROWS;
  double T0 = Sa4 - 2.0 * U4 + Sb4;
  double T1 = Sa2 - Sb2;
  double T2 = Sa3 - U3;
  double T4 = U2 - Sb3;
  double gw = (2.0 * n * T0 + 2.0 * T1 * T1 - 8.0 * (T2 * Sa - T4 * Sb) +
               4.0 * (Sa2 * Sa2 - 2.0 * U1 * U1 + Sb2 * Sb2)) /
              (n * n);
  double w = Sa2 + Sb2 - 2.0 * U1;
  return 0.9 * w + 0.1 * gw;
}

// K2: one block per projection p. Bitonic-sorts BOTH columns (post & prior)
// simultaneously (1024 CE pairs/stage = 1 per thread per array), computes
// the 16 f64 sums, evaluates both variants, atomicAdds min/P to out.
// Stages with j<=32 are wave-local under idx=((t&~(j-1))<<1)|(t&(j-1))
// (wave w touches exactly elements [128w,128w+128)), so no s_barrier there.
__global__ __launch_bounds__(1024) void rc_sortstats_kernel(
    const float* __restrict__ post_cm, const float* __restrict__ prior_cm,
    float* __restrict__ out) {
  __shared__ float sa[N_ROWS];
  __shared__ float sb[N_ROWS];
  __shared__ double sm[16][16];
  const int p = blockIdx.x;
  const int tid = threadIdx.x;
  sa[tid] = post_cm[p * N_ROWS + tid];
  sa[tid + 1024] = post_cm[p * N_ROWS + tid + 1024];
  sb[tid] = prior_cm[p * N_ROWS + tid];
  sb[tid + 1024] = prior_cm[p * N_ROWS + tid + 1024];
  __syncthreads();
  bool prev_big = false;
  for (unsigned k = 2; k <= N_ROWS; k <<= 1) {
    for (unsigned j = k >> 1; j > 0; j >>= 1) {
      const bool big = (j >= 64);
      if (big || prev_big)
        __syncthreads();
      else
        wave_lds_fence();
      unsigned idx = ((tid & ~(j - 1)) << 1) | (tid & (j - 1));
      unsigned ixj = idx | j;
      const bool up = (idx & k) == 0;
      float x = sa[idx], y = sa[ixj];
      if (up ? (x > y) : (x < y)) { sa[idx] = y; sa[ixj] = x; }
      float u = sb[idx], v = sb[ixj];
      if (up ? (u > v) : (u < v)) { sb[idx] = v; sb[ixj] = u; }
      prev_big = big;
    }
  }
  __syncthreads();
  // 16 sums: 0:Sa 1:Sb 2:Sa2 3:Sb2 4:Sa3 5:Sb3 6:Sa4 7:Sb4
  //          8:U1a 9:U2a 10:U3a 11:U4a (variant1: b aligned)
  //          12:U1b 13:U2b 14:U3b 15:U4b (variant2: b reversed)
  double S[16];
#pragma unroll
  for (int t = 0; t < 16; ++t) S[t] = 0.0;
  for (int i = tid; i < N_ROWS; i += 1024) {
    double a = (double)sa[i];
    double b = (double)sb[i];
    double br = (double)sb[N_ROWS - 1 - i];
    double a2 = a * a, b2 = b * b, br2 = br * br;
    S[0] += a;
    S[1] += b;
    S[2] += a2;
    S[3] += b2;
    S[4] += a2 * a;
    S[5] += b2 * b;
    S[6] += a2 * a2;
    S[7] += b2 * b2;
    S[8] += a * b;
    S[9] += a2 * b;
    S[10] += a * b2;
    S[11] += a2 * b2;
    S[12] += a * br;
    S[13] += a2 * br;
    S[14] += a * br2;
    S[15] += a2 * br2;
  }
#pragma unroll
  for (int t = 0; t < 16; ++t) S[t] = wave_reduce_d(S[t]);
  const int wave = tid >> 6, lane = tid & 63;
  if (lane == 0) {
#pragma unroll
    for (int t = 0; t < 16; ++t) sm[wave][t] = S[t];
  }
  __syncthreads();
  if (tid == 0) {
    double T[16];
#pragma unroll
    for (int t = 0; t < 16; ++t) {
      double acc = 0.0;
      for (int w = 0; w < 16; ++w) acc += sm[w][t];
      T[t] = acc;
    }
    double f1 = fgw_eval(T[0], T[1], T[2], T[3], T[4], T[5], T[6], T[7], T[8],
                         T[9], T[10], T[11]);
    double f2 = fgw_eval(T[0], T[1], T[2], T[3], T[4], T[5], T[6], T[7], T[12],
                         T[13], T[14], T[15]);
    atomicAdd(out, (float)(fmin(f1, f2) * (1.0 / P_DIM)));
  }
}

extern "C" void kernel_launch(void* const* d_in, const int* in_sizes, int n_in,
                              void* d_out, int out_size, void* d_ws,
                              size_t ws_size, hipStream_t stream) {
  const float4* z4 = (const float4*)d_in[0];
  const float4* g4 = (const float4*)d_in[1];
  const float* proj = (const float*)d_in[2];
  float* out = (float*)d_out;
  float* post_cm = (float*)d_ws;               // 2048*10 f32
  float* prior_cm = post_cm + N_ROWS * P_DIM;  // 2048*10 f32

  rc_proj_kernel<<<N_ROWS / 4, 256, 0, stream>>>(z4, g4, proj, post_cm,
                                                 prior_cm, out);
  rc_sortstats_kernel<<<P_DIM, 1024, 0, stream>>>(post_cm, prior_cm, out);
}